// Round 8
// baseline (446.148 us; speedup 1.0000x reference)
//
#include <hip/hip_runtime.h>
#include <hip/hip_bf16.h>
#include <cstdint>

#define DI __device__ __forceinline__

// B=4, T=2048, C=768, H=12, D=64
constexpr int Bz = 4, Tz = 2048, Cz = 768, Hz = 12, Dz = 64;
constexpr float QSCALE = 0.18033688011112042f;  // (1/8) * log2(e)

typedef __attribute__((ext_vector_type(4))) float f32x4;
typedef __attribute__((ext_vector_type(16))) float f32x16;
typedef __attribute__((ext_vector_type(8))) __bf16 bf16x8;
typedef __attribute__((ext_vector_type(4))) __bf16 bf16x4;
typedef __attribute__((ext_vector_type(2))) __bf16 bf16x2;

typedef __attribute__((address_space(1))) void gvoid;
typedef __attribute__((address_space(3))) void lvoid;

DI void gload16(const void* g, void* l) {
  __builtin_amdgcn_global_load_lds((gvoid*)g, (lvoid*)l, 16, 0, 0);
}

DI f32x4 mfma16(bf16x8 a, bf16x8 b, f32x4 c) {
  return __builtin_amdgcn_mfma_f32_16x16x32_bf16(a, b, c, 0, 0, 0);
}
DI f32x16 mfma32(bf16x8 a, bf16x8 b, f32x16 c) {
  return __builtin_amdgcn_mfma_f32_32x32x16_bf16(a, b, c, 0, 0, 0);
}

DI uint32_t pk2(float a, float b) {  // pack 2 f32 -> 2 bf16 in one u32
  bf16x2 t;
  t[0] = (__bf16)a;
  t[1] = (__bf16)b;
  return __builtin_bit_cast(uint32_t, t);
}

union FragU { bf16x8 v; uint32_t u[4]; };

// K LDS block swizzle: breaks both the row-start alias (rows are 128B ->
// bank depends only on blk) AND the 4-lane alias within l31&7 groups.
DI int kswz(int row) { return (row & 7) ^ (((row >> 3) & 3) << 1); }

// ---------------- one fused conversion kernel ----------------
__global__ void cvt_all_k(const float* __restrict__ x,
                          const float* __restrict__ wq, const float* __restrict__ wk,
                          const float* __restrict__ wv, __bf16* __restrict__ Xb,
                          __bf16* __restrict__ Wb) {
  int i = blockIdx.x * blockDim.x + threadIdx.x;  // < 2015232
  const float* s;
  __bf16* d;
  int r;
  if (i < 1572864) {
    s = x; d = Xb; r = i;
  } else {
    int j = i - 1572864;
    const int which = j / 147456;
    r = j - which * 147456;
    s = (which == 0) ? wq : (which == 1) ? wk : wv;
    d = Wb + which * 589824;  // 589824 bf16 elements per matrix
  }
  const float4 v = reinterpret_cast<const float4*>(s)[r];
  bf16x4 o = {(__bf16)v.x, (__bf16)v.y, (__bf16)v.z, (__bf16)v.w};
  reinterpret_cast<bf16x4*>(d)[r] = o;
}

// ---------------- fused QKV GEMM, 128x128 tile, BK=64 (r4-r7 form) ----
// Q pre-scaled by QSCALE; Q,K -> [bh][t][d]; V -> CHUNKED Vc[bh][k16][d][kc].
__global__ __launch_bounds__(256, 4) void qkv_gemm_k(
    const __bf16* __restrict__ Xb, const __bf16* __restrict__ Wb,
    const float* __restrict__ bq, const float* __restrict__ bk,
    const float* __restrict__ bv, __bf16* __restrict__ Qo,
    __bf16* __restrict__ Ko, __bf16* __restrict__ Vo) {
  __shared__ __align__(16) __bf16 As[128 * 64];
  __shared__ __align__(16) __bf16 Bs[128 * 64];

  const int tid = threadIdx.x;
  const int lane = tid & 63;
  const int w = tid >> 6;
  const int wr = w >> 1, wc = w & 1;
  const int g = lane >> 4, lr = lane & 15;

  const int wgid = (blockIdx.x & 7) * 144 + (blockIdx.x >> 3);
  const int tn = wgid % 18, tm = wgid / 18;
  const int m0 = tm * 128, n0 = tn * 128;

  f32x4 acc[4][4] = {};

  for (int kt = 0; kt < Cz; kt += 64) {
#pragma unroll
    for (int rep = 0; rep < 4; ++rep) {
      const int c = rep * 256 + tid;  // < 1024
      const int row = c >> 3, blk = c & 7;
      const int col = ((blk ^ (row & 7)) << 3);
      gload16(&Xb[(size_t)(m0 + row) * Cz + kt + col], &As[c << 3]);
      gload16(&Wb[(size_t)(n0 + row) * Cz + kt + col], &Bs[c << 3]);
    }
    __syncthreads();
#pragma unroll
    for (int kk = 0; kk < 2; ++kk) {
      bf16x8 a[4], b[4];
#pragma unroll
      for (int m = 0; m < 4; ++m) {
        const int row = wr * 64 + m * 16 + lr;
        a[m] = *reinterpret_cast<const bf16x8*>(
            &As[row * 64 + (((kk * 4 + g) ^ (row & 7)) << 3)]);
      }
#pragma unroll
      for (int n = 0; n < 4; ++n) {
        const int row = wc * 64 + n * 16 + lr;
        b[n] = *reinterpret_cast<const bf16x8*>(
            &Bs[row * 64 + (((kk * 4 + g) ^ (row & 7)) << 3)]);
      }
      __builtin_amdgcn_s_setprio(1);
#pragma unroll
      for (int m = 0; m < 4; ++m)
#pragma unroll
        for (int n = 0; n < 4; ++n) acc[m][n] = mfma16(a[m], b[n], acc[m][n]);
      __builtin_amdgcn_s_setprio(0);
    }
    __syncthreads();
  }

  // epilogue. tn 0-5 -> Q, 6-11 -> K, 12-17 -> V (uniform per block)
  const int bb = m0 >> 11;
  const int tbase = m0 & 2047;
  if (tn >= 12) {
#pragma unroll
    for (int n = 0; n < 4; ++n) {
      const int cc = (n0 - 1536) + wc * 64 + n * 16 + lr;
      const int h = cc >> 6, d = cc & 63;
      const float bsv = bv[cc];
      const int bh = bb * Hz + h;
#pragma unroll
      for (int m = 0; m < 4; ++m) {
        const int tloc = tbase + wr * 64 + m * 16 + g * 4;
        const int k16 = tloc >> 4;
        bf16x4 pkv;
#pragma unroll
        for (int j = 0; j < 4; ++j) pkv[j] = (__bf16)(acc[m][n][j] + bsv);
        *reinterpret_cast<bf16x4*>(
            &Vo[((size_t)(bh * 128 + k16) * 64 + d) * 16 + (tloc & 15)]) = pkv;
      }
    }
  } else {
    const bool isQ = (tn < 6);
#pragma unroll
    for (int n = 0; n < 4; ++n) {
      const int gn = n0 + wc * 64 + n * 16 + lr;
      const int cc = isQ ? gn : (gn - 768);
      const int h = cc >> 6, d = cc & 63;
      const float bsv = isQ ? bq[cc] : bk[cc];
      __bf16* dst = isQ ? Qo : Ko;
      const int bh = bb * Hz + h;
#pragma unroll
      for (int m = 0; m < 4; ++m) {
#pragma unroll
        for (int j = 0; j < 4; ++j) {
          const int t = tbase + wr * 64 + m * 16 + g * 4 + j;
          float v = acc[m][n][j] + bsv;
          if (isQ) v *= QSCALE;
          dst[(size_t)(bh * Tz + t) * Dz + d] = (__bf16)v;
        }
      }
    }
  }
}

// ---------------- flash attention, key-split 8-wave blocks ----------------
// grid 768 (48 bh x 16 q-tiles of 128), XCD-swizzled, 512 threads.
// Waves 0-3: keys 0-1023 for q-rows w*32..; waves 4-7: keys 1024-2047 for
// the SAME q-rows -> 6144 waves total = 24/CU (2x r7's 12): hides the
// serial QK->exp->pack->PV chain that r7's latency-bound profile exposed.
// Two independent K double-buffers (32KB LDS). V from global (chunked
// layout, coalesced, L2-hot). No-max softmax is order-independent -> the
// key-split combine (o_a+o_b, l_a+l_b) is exact, done in-LDS at the end
// (K buffers are dead by then). K swizzle upgraded to kswz(row) to break
// the 4-lane bank alias measured as +4cyc/read in r3-r7.
__global__ __launch_bounds__(512, 6) void attn_k(
    const __bf16* __restrict__ Qg, const __bf16* __restrict__ Kg,
    const __bf16* __restrict__ Vc, const float* __restrict__ mask,
    float* __restrict__ out) {
  __shared__ __align__(16) __bf16 KsAll[2][2][4096];  // [stream][buf][64x64]
  __shared__ int flag;

  const int tid = threadIdx.x;
  const int lane = tid & 63;
  const int w = tid >> 6;       // 0..7
  const int w4 = w & 3;         // q-position
  const int gw = w >> 2;        // key-stream
  const int hi = lane >> 5;
  const int l31 = lane & 31;

  // bijective XCD swizzle (768 % 8 == 0)
  const int wg = (blockIdx.x & 7) * 96 + (blockIdx.x >> 3);
  const int bh = wg >> 4, qt = wg & 15;
  const int bb = bh / Hz, h = bh - bb * Hz;
  const int q0 = qt * 128 + w4 * 32;
  const int kb0 = gw * 1024;  // this wave-group's key range base

  const size_t qkbase = (size_t)bh * Tz * Dz;
  const float* maskp = &mask[bb * Tz];

  if (tid == 0) flag = 0;
  __syncthreads();
  {
    int mybad = 0;
    for (int i = tid; i < Tz; i += 512) mybad |= (maskp[i] != 1.0f);
    if (__any(mybad) && lane == 0) atomicOr(&flag, 1);
  }

  // stage K tile 0 of BOTH streams (each thread: one 16B per stream)
  {
    const int c = tid;  // < 512 ; row = c>>3 in 0..63
    const int row = c >> 3, blk = c & 7;
    const int col = ((blk ^ kswz(row)) << 3);
    gload16(&Kg[qkbase + (size_t)row * Dz + col], &KsAll[0][0][c << 3]);
    gload16(&Kg[qkbase + (size_t)(1024 + row) * Dz + col], &KsAll[1][0][c << 3]);
  }

  // Q B-frags from global (pre-scaled): lane -> q = q0+l31, d = ks*16+hi*8
  bf16x8 qB[4];
#pragma unroll
  for (int ks = 0; ks < 4; ++ks)
    qB[ks] = *reinterpret_cast<const bf16x8*>(
        &Qg[qkbase + (size_t)(q0 + l31) * Dz + ks * 16 + hi * 8]);

  __syncthreads();  // flag final; also orders tile-0 stage (vmcnt drain)
  const bool use_mask = (flag != 0);

  // loop-invariant K LDS offsets. key = kblk*32+l31: kswz(key) == kswz-form
  // of l31 only (kblk*32 contributes (kblk*4)&3 == 0) -> kblk-independent.
  const int f31 = (l31 & 7) ^ (((l31 >> 3) & 3) << 1);
  const __bf16* ksBase = &KsAll[gw][0][0];  // wave-uniform stream base
  int off4[4];
#pragma unroll
  for (int i = 0; i < 4; ++i)
    off4[i] = l31 * 64 + (((i * 2 + hi) ^ f31) << 3);

  // V chunk lane offset: d=dblk*32+l31 -> (within chunk) d*16 + hi*8
  const int vlane0 = l31 * 16 + hi * 8;
  const size_t vcb0 = qkbase + (size_t)kb0 * Dz;  // chunked V, key-major

  f32x16 o0 = {}, o1 = {};
  float lpA = 0.f, lpB = 0.f;

  for (int t2 = 0; t2 < 8; ++t2) {
#pragma unroll
    for (int sub = 0; sub < 2; ++sub) {
      const int t = 2 * t2 + sub;
      // top barrier: buf[sub] (staged at t-1) drained; all waves done with
      // buf[sub^1] -> safe to overwrite below
      __syncthreads();

      // all 8 V fragment loads for this tile (coalesced 2KB/wave, L2-hot)
      bf16x8 vB[4][2];
#pragma unroll
      for (int ps4 = 0; ps4 < 4; ++ps4) {
        const size_t cb = vcb0 + (size_t)(t * 4 + ps4) * 1024;
        vB[ps4][0] = *reinterpret_cast<const bf16x8*>(&Vc[cb + vlane0]);
        vB[ps4][1] = *reinterpret_cast<const bf16x8*>(&Vc[cb + 512 + vlane0]);
      }

      // prefetch K tile t+1 for both streams into buf sub^1
      if (t < 15) {
        const int kt1 = (t + 1) * 64;
        const int c = tid;
        const int row = c >> 3, blk = c & 7;
        const int col = ((blk ^ kswz(row)) << 3);
        gload16(&Kg[qkbase + (size_t)(kt1 + row) * Dz + col],
                &KsAll[0][sub ^ 1][c << 3]);
        gload16(&Kg[qkbase + (size_t)(1024 + kt1 + row) * Dz + col],
                &KsAll[1][sub ^ 1][c << 3]);
      }
      const int kt = kb0 + t * 64;

#pragma unroll
      for (int kblk = 0; kblk < 2; ++kblk) {
        bf16x8 kA[4];
#pragma unroll
        for (int ks = 0; ks < 4; ++ks)
          kA[ks] = *reinterpret_cast<const bf16x8*>(
              &ksBase[sub * 4096 + kblk * 2048 + off4[ks]]);

        f32x16 s = {};
        __builtin_amdgcn_s_setprio(1);
#pragma unroll
        for (int ks = 0; ks < 4; ++ks) s = mfma32(kA[ks], qB[ks], s);
        __builtin_amdgcn_s_setprio(0);

        // p = exp2(s) (Q pre-scaled); reg r -> key (r&3)+8*(r>>2)+4*hi
        float p[16];
        if (use_mask) {
#pragma unroll
          for (int r = 0; r < 16; ++r) {
            const int kg = kt + kblk * 32 + (r & 3) + 8 * (r >> 2) + 4 * hi;
            p[r] = __builtin_amdgcn_exp2f(
                s[r] + (1.0f - maskp[kg]) * -14426.950408889634f);
            ((r & 1) ? lpB : lpA) += p[r];
          }
        } else {
#pragma unroll
          for (int r = 0; r < 16; ++r) {
            p[r] = __builtin_amdgcn_exp2f(s[r]);
            ((r & 1) ? lpB : lpA) += p[r];
          }
        }

        // T12 pack: keys {8m,8m+1}+4hi pairs + permlane32_swap
        uint32_t a0 = pk2(p[0], p[1]), a1 = pk2(p[4], p[5]);
        uint32_t a2 = pk2(p[8], p[9]), a3 = pk2(p[12], p[13]);
        uint32_t b0 = pk2(p[2], p[3]), b1 = pk2(p[6], p[7]);
        uint32_t b2 = pk2(p[10], p[11]), b3 = pk2(p[14], p[15]);
        asm volatile("v_permlane32_swap_b32 %0, %1" : "+v"(a0), "+v"(a1));
        asm volatile("v_permlane32_swap_b32 %0, %1" : "+v"(b0), "+v"(b1));
        asm volatile("v_permlane32_swap_b32 %0, %1" : "+v"(a2), "+v"(a3));
        asm volatile("v_permlane32_swap_b32 %0, %1" : "+v"(b2), "+v"(b3));
        FragU pf0, pf1;
        pf0.u[0] = a0; pf0.u[1] = b0; pf0.u[2] = a1; pf0.u[3] = b1;
        pf1.u[0] = a2; pf1.u[1] = b2; pf1.u[2] = a3; pf1.u[3] = b3;

        __builtin_amdgcn_s_setprio(1);
        o0 = mfma32(pf0.v, vB[kblk * 2][0], o0);
        o1 = mfma32(pf0.v, vB[kblk * 2][1], o1);
        o0 = mfma32(pf1.v, vB[kblk * 2 + 1][0], o0);
        o1 = mfma32(pf1.v, vB[kblk * 2 + 1][1], o1);
        __builtin_amdgcn_s_setprio(0);
      }
    }
  }

  // ---- key-split combine (exact: no-max softmax is order-independent) ----
  // K buffers are dead; reuse as f32 scratch. Phase 1: o0; phase 2: o1+l.
  float* cb = (float*)&KsAll[0][0][0];
  float lp = lpA + lpB;
  __syncthreads();
  if (gw == 1)
#pragma unroll
    for (int j = 0; j < 16; ++j) cb[w4 * 1024 + lane * 16 + j] = o0[j];
  __syncthreads();
  if (gw == 0)
#pragma unroll
    for (int j = 0; j < 16; ++j) o0[j] += cb[w4 * 1024 + lane * 16 + j];
  __syncthreads();
  if (gw == 1) {
#pragma unroll
    for (int j = 0; j < 16; ++j) cb[w4 * 1024 + lane * 16 + j] = o1[j];
    cb[4096 + w4 * 64 + lane] = lp;
  }
  __syncthreads();
  if (gw == 0) {
#pragma unroll
    for (int j = 0; j < 16; ++j) o1[j] += cb[w4 * 1024 + lane * 16 + j];
    lp += cb[4096 + w4 * 64 + lane];

    // epilogue: O layout col=d=l31(+32*dblk), row=q=(r&3)+8*(r>>2)+4*hi
    float lfin = lp + __shfl_xor(lp, 32);
    const float inv = 1.0f / lfin;
#pragma unroll
    for (int r = 0; r < 16; ++r) {
      const int qr = (r & 3) + 8 * (r >> 2) + 4 * hi;
      const float invr = __shfl(inv, qr);  // lanes 0..31 hold inv for q=lane
      float* orow = &out[(size_t)(bb * Tz + q0 + qr) * Cz + h * Dz + l31];
      orow[0] = o0[r] * invr;
      orow[32] = o1[r] * invr;
    }
  }
}

// ---------------- launcher ----------------
extern "C" void kernel_launch(void* const* d_in, const int* in_sizes, int n_in,
                              void* d_out, int out_size, void* d_ws,
                              size_t ws_size, hipStream_t stream) {
  const float* x = (const float*)d_in[0];
  const float* mask = (const float*)d_in[1];
  const float* Wq = (const float*)d_in[2];
  const float* bq = (const float*)d_in[3];
  const float* Wk = (const float*)d_in[4];
  const float* bk = (const float*)d_in[5];
  const float* Wv = (const float*)d_in[6];
  const float* bv = (const float*)d_in[7];
  float* out = (float*)d_out;

  char* ws = (char*)d_ws;
  __bf16* Xb = (__bf16*)ws;                              // 8192*768 bf16
  __bf16* Wb = (__bf16*)(ws + 12582912);                 // 2304*768 bf16
  __bf16* Qb = (__bf16*)(ws + 16131072);                 // [bh][t][d], pre-scaled
  __bf16* Kb = (__bf16*)(ws + 16131072 + 12582912);      // [bh][t][d]
  __bf16* Vb = (__bf16*)(ws + 16131072 + 2 * 12582912);  // chunked [bh][k16][d][kc]

  cvt_all_k<<<7872, 256, 0, stream>>>(x, Wq, Wk, Wv, Xb, Wb);
  qkv_gemm_k<<<1152, 256, 0, stream>>>(Xb, Wb, bq, bk, bv, Qb, Kb, Vb);
  attn_k<<<768, 512, 0, stream>>>(Qb, Kb, Vb, mask, out);
}

// Round 9
// 252.507 us; speedup vs baseline: 1.7669x; 1.7669x over previous
//
#include <hip/hip_runtime.h>
#include <hip/hip_bf16.h>
#include <cstdint>

#define DI __device__ __forceinline__

// B=4, T=2048, C=768, H=12, D=64
constexpr int Bz = 4, Tz = 2048, Cz = 768, Hz = 12, Dz = 64;
constexpr float QSCALE = 0.18033688011112042f;  // (1/8) * log2(e)

typedef __attribute__((ext_vector_type(4))) float f32x4;
typedef __attribute__((ext_vector_type(16))) float f32x16;
typedef __attribute__((ext_vector_type(8))) __bf16 bf16x8;
typedef __attribute__((ext_vector_type(4))) __bf16 bf16x4;
typedef __attribute__((ext_vector_type(2))) __bf16 bf16x2;

typedef __attribute__((address_space(1))) void gvoid;
typedef __attribute__((address_space(3))) void lvoid;

DI void gload16(const void* g, void* l) {
  __builtin_amdgcn_global_load_lds((gvoid*)g, (lvoid*)l, 16, 0, 0);
}

DI f32x4 mfma16(bf16x8 a, bf16x8 b, f32x4 c) {
  return __builtin_amdgcn_mfma_f32_16x16x32_bf16(a, b, c, 0, 0, 0);
}
DI f32x16 mfma32(bf16x8 a, bf16x8 b, f32x16 c) {
  return __builtin_amdgcn_mfma_f32_32x32x16_bf16(a, b, c, 0, 0, 0);
}

DI uint32_t pk2(float a, float b) {  // pack 2 f32 -> 2 bf16 in one u32
  bf16x2 t;
  t[0] = (__bf16)a;
  t[1] = (__bf16)b;
  return __builtin_bit_cast(uint32_t, t);
}

union FragU { bf16x8 v; uint32_t u[4]; };

// ---------------- one fused conversion kernel ----------------
__global__ void cvt_all_k(const float* __restrict__ x,
                          const float* __restrict__ wq, const float* __restrict__ wk,
                          const float* __restrict__ wv, __bf16* __restrict__ Xb,
                          __bf16* __restrict__ Wb) {
  int i = blockIdx.x * blockDim.x + threadIdx.x;  // < 2015232
  const float* s;
  __bf16* d;
  int r;
  if (i < 1572864) {
    s = x; d = Xb; r = i;
  } else {
    int j = i - 1572864;
    const int which = j / 147456;
    r = j - which * 147456;
    s = (which == 0) ? wq : (which == 1) ? wk : wv;
    d = Wb + which * 589824;  // 589824 bf16 elements per matrix
  }
  const float4 v = reinterpret_cast<const float4*>(s)[r];
  bf16x4 o = {(__bf16)v.x, (__bf16)v.y, (__bf16)v.z, (__bf16)v.w};
  reinterpret_cast<bf16x4*>(d)[r] = o;
}

// ---------------- fused QKV GEMM, 128x128 tile, BK=64 (r4-r7 form) ----
// Q pre-scaled by QSCALE; Q,K -> [bh][t][d]; V -> CHUNKED Vc[bh][k16][d][kc].
__global__ __launch_bounds__(256, 4) void qkv_gemm_k(
    const __bf16* __restrict__ Xb, const __bf16* __restrict__ Wb,
    const float* __restrict__ bq, const float* __restrict__ bk,
    const float* __restrict__ bv, __bf16* __restrict__ Qo,
    __bf16* __restrict__ Ko, __bf16* __restrict__ Vo) {
  __shared__ __align__(16) __bf16 As[128 * 64];
  __shared__ __align__(16) __bf16 Bs[128 * 64];

  const int tid = threadIdx.x;
  const int lane = tid & 63;
  const int w = tid >> 6;
  const int wr = w >> 1, wc = w & 1;
  const int g = lane >> 4, lr = lane & 15;

  const int wgid = (blockIdx.x & 7) * 144 + (blockIdx.x >> 3);
  const int tn = wgid % 18, tm = wgid / 18;
  const int m0 = tm * 128, n0 = tn * 128;

  f32x4 acc[4][4] = {};

  for (int kt = 0; kt < Cz; kt += 64) {
#pragma unroll
    for (int rep = 0; rep < 4; ++rep) {
      const int c = rep * 256 + tid;  // < 1024
      const int row = c >> 3, blk = c & 7;
      const int col = ((blk ^ (row & 7)) << 3);
      gload16(&Xb[(size_t)(m0 + row) * Cz + kt + col], &As[c << 3]);
      gload16(&Wb[(size_t)(n0 + row) * Cz + kt + col], &Bs[c << 3]);
    }
    __syncthreads();
#pragma unroll
    for (int kk = 0; kk < 2; ++kk) {
      bf16x8 a[4], b[4];
#pragma unroll
      for (int m = 0; m < 4; ++m) {
        const int row = wr * 64 + m * 16 + lr;
        a[m] = *reinterpret_cast<const bf16x8*>(
            &As[row * 64 + (((kk * 4 + g) ^ (row & 7)) << 3)]);
      }
#pragma unroll
      for (int n = 0; n < 4; ++n) {
        const int row = wc * 64 + n * 16 + lr;
        b[n] = *reinterpret_cast<const bf16x8*>(
            &Bs[row * 64 + (((kk * 4 + g) ^ (row & 7)) << 3)]);
      }
      __builtin_amdgcn_s_setprio(1);
#pragma unroll
      for (int m = 0; m < 4; ++m)
#pragma unroll
        for (int n = 0; n < 4; ++n) acc[m][n] = mfma16(a[m], b[n], acc[m][n]);
      __builtin_amdgcn_s_setprio(0);
    }
    __syncthreads();
  }

  // epilogue. tn 0-5 -> Q, 6-11 -> K, 12-17 -> V (uniform per block)
  const int bb = m0 >> 11;
  const int tbase = m0 & 2047;
  if (tn >= 12) {
#pragma unroll
    for (int n = 0; n < 4; ++n) {
      const int cc = (n0 - 1536) + wc * 64 + n * 16 + lr;
      const int h = cc >> 6, d = cc & 63;
      const float bsv = bv[cc];
      const int bh = bb * Hz + h;
#pragma unroll
      for (int m = 0; m < 4; ++m) {
        const int tloc = tbase + wr * 64 + m * 16 + g * 4;
        const int k16 = tloc >> 4;
        bf16x4 pkv;
#pragma unroll
        for (int j = 0; j < 4; ++j) pkv[j] = (__bf16)(acc[m][n][j] + bsv);
        *reinterpret_cast<bf16x4*>(
            &Vo[((size_t)(bh * 128 + k16) * 64 + d) * 16 + (tloc & 15)]) = pkv;
      }
    }
  } else {
    const bool isQ = (tn < 6);
#pragma unroll
    for (int n = 0; n < 4; ++n) {
      const int gn = n0 + wc * 64 + n * 16 + lr;
      const int cc = isQ ? gn : (gn - 768);
      const int h = cc >> 6, d = cc & 63;
      const float bsv = isQ ? bq[cc] : bk[cc];
      __bf16* dst = isQ ? Qo : Ko;
      const int bh = bb * Hz + h;
#pragma unroll
      for (int m = 0; m < 4; ++m) {
#pragma unroll
        for (int j = 0; j < 4; ++j) {
          const int t = tbase + wr * 64 + m * 16 + g * 4 + j;
          float v = acc[m][n][j] + bsv;
          if (isQ) v *= QSCALE;
          dst[(size_t)(bh * Tz + t) * Dz + d] = (__bf16)v;
        }
      }
    }
  }
}

// ---------------- attention main loop (templated on mask path) ----------
// Fast path (MASKED=false): 4-deep K LDS ring, prefetch K(t+2); per-tile
// tail = sched_barrier(0) + s_waitcnt vmcnt(2) + s_barrier. vmcnt(2) keeps
// ONLY the 2 newest gload_lds (K(t+2)) in flight: everything older --
// including K(t+1)'s LDS writes -- has landed before any wave crosses the
// barrier (cross-wave LDS visibility). sched_barrier(0) pins instruction
// placement (rule-#18 sinking hazard). No per-tile vmcnt(0) drain.
// Slow path (MASKED=true): mask loads inside the loop perturb vmem
// counting -> plain __syncthreads (full drain), correctness-first.
template <bool MASKED>
DI void attn_main(__bf16 (*Ks)[4096], const __bf16* __restrict__ Kg,
                  const __bf16* __restrict__ Vc, const float* maskp,
                  size_t qkbase, size_t vcb0, const bf16x8* qB,
                  const int* off4, int vlane0, int tid, int hi,
                  f32x16& o0, f32x16& o1, float& lpA, float& lpB) {
  for (int t4 = 0; t4 < 8; ++t4) {
#pragma unroll
    for (int sub = 0; sub < 4; ++sub) {
      const int t = 4 * t4 + sub;
      // prefetch K(t+2) into ring slot (sub+2)&3
      if (t < 30) {
        const int kt2 = (t + 2) * 64;
#pragma unroll
        for (int rep = 0; rep < 2; ++rep) {
          const int c = rep * 256 + tid;
          const int row = c >> 3, blk = c & 7;
          const int col = ((blk ^ (row & 7)) << 3);
          gload16(&Kg[qkbase + (size_t)(kt2 + row) * Dz + col],
                  &Ks[(sub + 2) & 3][c << 3]);
        }
      }
      // all 8 V fragment loads for this tile (coalesced 2KB/wave, L2-hot)
      bf16x8 vB[4][2];
#pragma unroll
      for (int ps4 = 0; ps4 < 4; ++ps4) {
        const size_t cb = vcb0 + (size_t)(t * 4 + ps4) * 1024;
        vB[ps4][0] = *reinterpret_cast<const bf16x8*>(&Vc[cb + vlane0]);
        vB[ps4][1] = *reinterpret_cast<const bf16x8*>(&Vc[cb + 512 + vlane0]);
      }
      const int kt = t * 64;

#pragma unroll
      for (int kblk = 0; kblk < 2; ++kblk) {
        bf16x8 kA[4];
#pragma unroll
        for (int ks = 0; ks < 4; ++ks)
          kA[ks] = *reinterpret_cast<const bf16x8*>(
              &Ks[sub][kblk * 2048 + off4[ks]]);

        f32x16 s = {};
        __builtin_amdgcn_s_setprio(1);
#pragma unroll
        for (int ks = 0; ks < 4; ++ks) s = mfma32(kA[ks], qB[ks], s);
        __builtin_amdgcn_s_setprio(0);

        // p = exp2(s) (Q pre-scaled); reg r -> key (r&3)+8*(r>>2)+4*hi
        float p[16];
#pragma unroll
        for (int r = 0; r < 16; ++r) {
          float sc = s[r];
          if (MASKED) {
            const int kg = kt + kblk * 32 + (r & 3) + 8 * (r >> 2) + 4 * hi;
            sc += (1.0f - maskp[kg]) * -14426.950408889634f;
          }
          p[r] = __builtin_amdgcn_exp2f(sc);
          ((r & 1) ? lpB : lpA) += p[r];
        }

        // T12 pack: keys {8m,8m+1}+4hi pairs + permlane32_swap
        uint32_t a0 = pk2(p[0], p[1]), a1 = pk2(p[4], p[5]);
        uint32_t a2 = pk2(p[8], p[9]), a3 = pk2(p[12], p[13]);
        uint32_t b0 = pk2(p[2], p[3]), b1 = pk2(p[6], p[7]);
        uint32_t b2 = pk2(p[10], p[11]), b3 = pk2(p[14], p[15]);
        asm volatile("v_permlane32_swap_b32 %0, %1" : "+v"(a0), "+v"(a1));
        asm volatile("v_permlane32_swap_b32 %0, %1" : "+v"(b0), "+v"(b1));
        asm volatile("v_permlane32_swap_b32 %0, %1" : "+v"(a2), "+v"(a3));
        asm volatile("v_permlane32_swap_b32 %0, %1" : "+v"(b2), "+v"(b3));
        FragU pf0, pf1;
        pf0.u[0] = a0; pf0.u[1] = b0; pf0.u[2] = a1; pf0.u[3] = b1;
        pf1.u[0] = a2; pf1.u[1] = b2; pf1.u[2] = a3; pf1.u[3] = b3;

        __builtin_amdgcn_s_setprio(1);
        o0 = mfma32(pf0.v, vB[kblk * 2][0], o0);
        o1 = mfma32(pf0.v, vB[kblk * 2][1], o1);
        o0 = mfma32(pf1.v, vB[kblk * 2 + 1][0], o0);
        o1 = mfma32(pf1.v, vB[kblk * 2 + 1][1], o1);
        __builtin_amdgcn_s_setprio(0);
      }

      if (MASKED) {
        __syncthreads();
      } else {
        __builtin_amdgcn_sched_barrier(0);
        asm volatile("s_waitcnt vmcnt(2)" ::: "memory");
        __builtin_amdgcn_s_barrier();
        __builtin_amdgcn_sched_barrier(0);
      }
    }
  }
}

// ---------------- flash attention ----------------
// r7 structure (grid 768 = 48 bh x 16 q-tiles, XCD-swizzled, 4 waves x
// 32 q, K in LDS, V from global in chunked layout) + counted-vmcnt
// pipeline (see attn_main). LDS = 4 x 8KB K ring.
__global__ __launch_bounds__(256, 4) void attn_k(
    const __bf16* __restrict__ Qg, const __bf16* __restrict__ Kg,
    const __bf16* __restrict__ Vc, const float* __restrict__ mask,
    float* __restrict__ out) {
  __shared__ __align__(16) __bf16 Ks[4][4096];
  __shared__ int flag;

  const int tid = threadIdx.x;
  const int lane = tid & 63;
  const int w = tid >> 6;  // 0..3
  const int hi = lane >> 5;
  const int l31 = lane & 31;

  // bijective XCD swizzle (768 % 8 == 0)
  const int wg = (blockIdx.x & 7) * 96 + (blockIdx.x >> 3);
  const int bh = wg >> 4, qt = wg & 15;
  const int bb = bh / Hz, h = bh - bb * Hz;
  const int q0 = qt * 128 + w * 32;

  const size_t qkbase = (size_t)bh * Tz * Dz;
  const float* maskp = &mask[bb * Tz];

  if (tid == 0) flag = 0;
  __syncthreads();
  {
    int mybad = 0;
    for (int i = tid; i < Tz; i += 256) mybad |= (maskp[i] != 1.0f);
    if (__any(mybad) && lane == 0) atomicOr(&flag, 1);
  }

  // stage K tiles 0 and 1 into ring slots 0,1
#pragma unroll
  for (int tt = 0; tt < 2; ++tt) {
#pragma unroll
    for (int rep = 0; rep < 2; ++rep) {
      const int c = rep * 256 + tid;  // < 512
      const int row = c >> 3, blk = c & 7;
      const int col = ((blk ^ (row & 7)) << 3);
      gload16(&Kg[qkbase + (size_t)(tt * 64 + row) * Dz + col],
              &Ks[tt][c << 3]);
    }
  }

  // Q B-frags from global (pre-scaled): lane -> q = q0+l31, d = ks*16+hi*8
  bf16x8 qB[4];
#pragma unroll
  for (int ks = 0; ks < 4; ++ks)
    qB[ks] = *reinterpret_cast<const bf16x8*>(
        &Qg[qkbase + (size_t)(q0 + l31) * Dz + ks * 16 + hi * 8]);

  __syncthreads();  // full drain: flag final, K0/K1 staged and landed
  const bool use_mask = (flag != 0);

  // loop-invariant K LDS offsets; (row&7)==(l31&7), kblk adds 2048 elems
  int off4[4];
#pragma unroll
  for (int i = 0; i < 4; ++i)
    off4[i] = l31 * 64 + (((i * 2 + hi) ^ (l31 & 7)) << 3);

  // V chunk lane offset: d=dblk*32+l31 -> (within chunk) d*16 + hi*8
  const int vlane0 = l31 * 16 + hi * 8;
  const size_t vcb0 = qkbase;  // chunked V, key-major, same extent

  f32x16 o0 = {}, o1 = {};
  float lpA = 0.f, lpB = 0.f;

  if (use_mask)
    attn_main<true>(Ks, Kg, Vc, maskp, qkbase, vcb0, qB, off4, vlane0, tid,
                    hi, o0, o1, lpA, lpB);
  else
    attn_main<false>(Ks, Kg, Vc, maskp, qkbase, vcb0, qB, off4, vlane0, tid,
                     hi, o0, o1, lpA, lpB);

  // epilogue: O layout col=d=l31(+32*dblk), row=q=(r&3)+8*(r>>2)+4*hi
  float lp = lpA + lpB;
  float lfin = lp + __shfl_xor(lp, 32);
  const float inv = 1.0f / lfin;
#pragma unroll
  for (int r = 0; r < 16; ++r) {
    const int qr = (r & 3) + 8 * (r >> 2) + 4 * hi;
    const float invr = __shfl(inv, qr);  // lanes 0..31 hold inv for q=lane
    float* orow = &out[(size_t)(bb * Tz + q0 + qr) * Cz + h * Dz + l31];
    orow[0] = o0[r] * invr;
    orow[32] = o1[r] * invr;
  }
}

// ---------------- launcher ----------------
extern "C" void kernel_launch(void* const* d_in, const int* in_sizes, int n_in,
                              void* d_out, int out_size, void* d_ws,
                              size_t ws_size, hipStream_t stream) {
  const float* x = (const float*)d_in[0];
  const float* mask = (const float*)d_in[1];
  const float* Wq = (const float*)d_in[2];
  const float* bq = (const float*)d_in[3];
  const float* Wk = (const float*)d_in[4];
  const float* bk = (const float*)d_in[5];
  const float* Wv = (const float*)d_in[6];
  const float* bv = (const float*)d_in[7];
  float* out = (float*)d_out;

  char* ws = (char*)d_ws;
  __bf16* Xb = (__bf16*)ws;                              // 8192*768 bf16
  __bf16* Wb = (__bf16*)(ws + 12582912);                 // 2304*768 bf16
  __bf16* Qb = (__bf16*)(ws + 16131072);                 // [bh][t][d], pre-scaled
  __bf16* Kb = (__bf16*)(ws + 16131072 + 12582912);      // [bh][t][d]
  __bf16* Vb = (__bf16*)(ws + 16131072 + 2 * 12582912);  // chunked [bh][k16][d][kc]

  cvt_all_k<<<7872, 256, 0, stream>>>(x, Wq, Wk, Wv, Xb, Wb);
  qkv_gemm_k<<<1152, 256, 0, stream>>>(Xb, Wb, bq, bk, bv, Qb, Kb, Vb);
  attn_k<<<768, 256, 0, stream>>>(Qb, Kb, Vb, mask, out);
}

// Round 10
// 117.335 us; speedup vs baseline: 3.8023x; 2.1520x over previous
//
#include <hip/hip_runtime.h>
#include <hip/hip_bf16.h>
#include <cstdint>

#define DI __device__ __forceinline__

// B=4, T=2048, C=768, H=12, D=64
constexpr int Bz = 4, Tz = 2048, Cz = 768, Hz = 12, Dz = 64;
constexpr float QSCALE = 0.18033688011112042f;  // (1/8) * log2(e)

typedef __attribute__((ext_vector_type(4))) float f32x4;
typedef __attribute__((ext_vector_type(16))) float f32x16;
typedef __attribute__((ext_vector_type(8))) __bf16 bf16x8;
typedef __attribute__((ext_vector_type(4))) __bf16 bf16x4;
typedef __attribute__((ext_vector_type(2))) __bf16 bf16x2;

typedef __attribute__((address_space(1))) void gvoid;
typedef __attribute__((address_space(3))) void lvoid;

DI void gload16(const void* g, void* l) {
  __builtin_amdgcn_global_load_lds((gvoid*)g, (lvoid*)l, 16, 0, 0);
}

DI f32x4 mfma16(bf16x8 a, bf16x8 b, f32x4 c) {
  return __builtin_amdgcn_mfma_f32_16x16x32_bf16(a, b, c, 0, 0, 0);
}
DI f32x16 mfma32(bf16x8 a, bf16x8 b, f32x16 c) {
  return __builtin_amdgcn_mfma_f32_32x32x16_bf16(a, b, c, 0, 0, 0);
}

DI uint32_t pk2(float a, float b) {  // pack 2 f32 -> 2 bf16 in one u32
  bf16x2 t;
  t[0] = (__bf16)a;
  t[1] = (__bf16)b;
  return __builtin_bit_cast(uint32_t, t);
}

union FragU { bf16x8 v; uint32_t u[4]; };

// ---------------- one fused conversion kernel ----------------
__global__ void cvt_all_k(const float* __restrict__ x,
                          const float* __restrict__ wq, const float* __restrict__ wk,
                          const float* __restrict__ wv, __bf16* __restrict__ Xb,
                          __bf16* __restrict__ Wb) {
  int i = blockIdx.x * blockDim.x + threadIdx.x;  // < 2015232
  const float* s;
  __bf16* d;
  int r;
  if (i < 1572864) {
    s = x; d = Xb; r = i;
  } else {
    int j = i - 1572864;
    const int which = j / 147456;
    r = j - which * 147456;
    s = (which == 0) ? wq : (which == 1) ? wk : wv;
    d = Wb + which * 589824;  // 589824 bf16 elements per matrix
  }
  const float4 v = reinterpret_cast<const float4*>(s)[r];
  bf16x4 o = {(__bf16)v.x, (__bf16)v.y, (__bf16)v.z, (__bf16)v.w};
  reinterpret_cast<bf16x4*>(d)[r] = o;
}

// ---------------- fused QKV GEMM, 128x128 tile, BK=64 (r4-r7 form) ----
// Q pre-scaled by QSCALE; Q,K -> [bh][t][d]; V -> CHUNKED Vc[bh][k16][d][kc].
__global__ __launch_bounds__(256, 4) void qkv_gemm_k(
    const __bf16* __restrict__ Xb, const __bf16* __restrict__ Wb,
    const float* __restrict__ bq, const float* __restrict__ bk,
    const float* __restrict__ bv, __bf16* __restrict__ Qo,
    __bf16* __restrict__ Ko, __bf16* __restrict__ Vo) {
  __shared__ __align__(16) __bf16 As[128 * 64];
  __shared__ __align__(16) __bf16 Bs[128 * 64];

  const int tid = threadIdx.x;
  const int lane = tid & 63;
  const int w = tid >> 6;
  const int wr = w >> 1, wc = w & 1;
  const int g = lane >> 4, lr = lane & 15;

  const int wgid = (blockIdx.x & 7) * 144 + (blockIdx.x >> 3);
  const int tn = wgid % 18, tm = wgid / 18;
  const int m0 = tm * 128, n0 = tn * 128;

  f32x4 acc[4][4] = {};

  for (int kt = 0; kt < Cz; kt += 64) {
#pragma unroll
    for (int rep = 0; rep < 4; ++rep) {
      const int c = rep * 256 + tid;  // < 1024
      const int row = c >> 3, blk = c & 7;
      const int col = ((blk ^ (row & 7)) << 3);
      gload16(&Xb[(size_t)(m0 + row) * Cz + kt + col], &As[c << 3]);
      gload16(&Wb[(size_t)(n0 + row) * Cz + kt + col], &Bs[c << 3]);
    }
    __syncthreads();
#pragma unroll
    for (int kk = 0; kk < 2; ++kk) {
      bf16x8 a[4], b[4];
#pragma unroll
      for (int m = 0; m < 4; ++m) {
        const int row = wr * 64 + m * 16 + lr;
        a[m] = *reinterpret_cast<const bf16x8*>(
            &As[row * 64 + (((kk * 4 + g) ^ (row & 7)) << 3)]);
      }
#pragma unroll
      for (int n = 0; n < 4; ++n) {
        const int row = wc * 64 + n * 16 + lr;
        b[n] = *reinterpret_cast<const bf16x8*>(
            &Bs[row * 64 + (((kk * 4 + g) ^ (row & 7)) << 3)]);
      }
      __builtin_amdgcn_s_setprio(1);
#pragma unroll
      for (int m = 0; m < 4; ++m)
#pragma unroll
        for (int n = 0; n < 4; ++n) acc[m][n] = mfma16(a[m], b[n], acc[m][n]);
      __builtin_amdgcn_s_setprio(0);
    }
    __syncthreads();
  }

  // epilogue. tn 0-5 -> Q, 6-11 -> K, 12-17 -> V (uniform per block)
  const int bb = m0 >> 11;
  const int tbase = m0 & 2047;
  if (tn >= 12) {
#pragma unroll
    for (int n = 0; n < 4; ++n) {
      const int cc = (n0 - 1536) + wc * 64 + n * 16 + lr;
      const int h = cc >> 6, d = cc & 63;
      const float bsv = bv[cc];
      const int bh = bb * Hz + h;
#pragma unroll
      for (int m = 0; m < 4; ++m) {
        const int tloc = tbase + wr * 64 + m * 16 + g * 4;
        const int k16 = tloc >> 4;
        bf16x4 pkv;
#pragma unroll
        for (int j = 0; j < 4; ++j) pkv[j] = (__bf16)(acc[m][n][j] + bsv);
        *reinterpret_cast<bf16x4*>(
            &Vo[((size_t)(bh * 128 + k16) * 64 + d) * 16 + (tloc & 15)]) = pkv;
      }
    }
  } else {
    const bool isQ = (tn < 6);
#pragma unroll
    for (int n = 0; n < 4; ++n) {
      const int gn = n0 + wc * 64 + n * 16 + lr;
      const int cc = isQ ? gn : (gn - 768);
      const int h = cc >> 6, d = cc & 63;
      const float bsv = isQ ? bq[cc] : bk[cc];
      __bf16* dst = isQ ? Qo : Ko;
      const int bh = bb * Hz + h;
#pragma unroll
      for (int m = 0; m < 4; ++m) {
#pragma unroll
        for (int j = 0; j < 4; ++j) {
          const int t = tbase + wr * 64 + m * 16 + g * 4 + j;
          float v = acc[m][n][j] + bsv;
          if (isQ) v *= QSCALE;
          dst[(size_t)(bh * Tz + t) * Dz + d] = (__bf16)v;
        }
      }
    }
  }
}

// per-kblk compute: QK^T -> exp2 -> T12 pack -> PV. All-register.
#define KBLK_BODY(KBLK, MASKED)                                               \
  {                                                                           \
    bf16x8 kA0 = *reinterpret_cast<const bf16x8*>(                            \
        &Ks[sub][(KBLK)*2048 + off4[0]]);                                     \
    bf16x8 kA1 = *reinterpret_cast<const bf16x8*>(                            \
        &Ks[sub][(KBLK)*2048 + off4[1]]);                                     \
    bf16x8 kA2 = *reinterpret_cast<const bf16x8*>(                            \
        &Ks[sub][(KBLK)*2048 + off4[2]]);                                     \
    bf16x8 kA3 = *reinterpret_cast<const bf16x8*>(                            \
        &Ks[sub][(KBLK)*2048 + off4[3]]);                                     \
    f32x16 s = {};                                                            \
    __builtin_amdgcn_s_setprio(1);                                            \
    s = mfma32(kA0, qB[0], s);                                                \
    s = mfma32(kA1, qB[1], s);                                                \
    s = mfma32(kA2, qB[2], s);                                                \
    s = mfma32(kA3, qB[3], s);                                                \
    __builtin_amdgcn_s_setprio(0);                                            \
    float p[16];                                                              \
    _Pragma("unroll") for (int r = 0; r < 16; ++r) {                          \
      float sc = s[r];                                                        \
      if (MASKED) {                                                           \
        const int kg = kt + (KBLK)*32 + (r & 3) + 8 * (r >> 2) + 4 * hi;      \
        sc += (1.0f - maskp[kg]) * -14426.950408889634f;                      \
      }                                                                       \
      p[r] = __builtin_amdgcn_exp2f(sc);                                      \
      ((r & 1) ? lpB : lpA) += p[r];                                          \
    }                                                                         \
    uint32_t a0 = pk2(p[0], p[1]), a1 = pk2(p[4], p[5]);                      \
    uint32_t a2 = pk2(p[8], p[9]), a3 = pk2(p[12], p[13]);                    \
    uint32_t b0 = pk2(p[2], p[3]), b1 = pk2(p[6], p[7]);                      \
    uint32_t b2 = pk2(p[10], p[11]), b3 = pk2(p[14], p[15]);                  \
    asm volatile("v_permlane32_swap_b32 %0, %1" : "+v"(a0), "+v"(a1));        \
    asm volatile("v_permlane32_swap_b32 %0, %1" : "+v"(b0), "+v"(b1));        \
    asm volatile("v_permlane32_swap_b32 %0, %1" : "+v"(a2), "+v"(a3));        \
    asm volatile("v_permlane32_swap_b32 %0, %1" : "+v"(b2), "+v"(b3));        \
    FragU pf0, pf1;                                                           \
    pf0.u[0] = a0; pf0.u[1] = b0; pf0.u[2] = a1; pf0.u[3] = b1;               \
    pf1.u[0] = a2; pf1.u[1] = b2; pf1.u[2] = a3; pf1.u[3] = b3;               \
    __builtin_amdgcn_s_setprio(1);                                            \
    o0 = mfma32(pf0.v, vB[(KBLK)*2][0], o0);                                  \
    o1 = mfma32(pf0.v, vB[(KBLK)*2][1], o1);                                  \
    o0 = mfma32(pf1.v, vB[(KBLK)*2 + 1][0], o0);                              \
    o1 = mfma32(pf1.v, vB[(KBLK)*2 + 1][1], o1);                              \
    __builtin_amdgcn_s_setprio(0);                                            \
  }

// ---------------- flash attention ----------------
// r7 dataflow (grid 768 = 48 bh x 16 q-tiles, XCD-swizzled, 4 waves x 32 q,
// K in LDS, V from global chunked) + counted-vmcnt pipeline:
// 4-slot K ring, prefetch K(t+2). Per-tile ISSUE ORDER: vB global loads
// FIRST, K-prefetch LAST -> vmcnt retire order makes iter t's vB
// consumption prove K(t+1) landed, and the tail (sched_barrier; s_waitcnt
// vmcnt(2); s_barrier; sched_barrier) keeps only K(t+2) in flight across
// the barrier. No vmcnt(0) drain anywhere in the loop. No "memory"
// clobber; no address-taken locals near asm (r9's spill trigger).
// Mask!=all-ones path: plain __syncthreads() tail (full drain).
__global__ __launch_bounds__(256, 3) void attn_k(
    const __bf16* __restrict__ Qg, const __bf16* __restrict__ Kg,
    const __bf16* __restrict__ Vc, const float* __restrict__ mask,
    float* __restrict__ out) {
  __shared__ __align__(16) __bf16 Ks[4][4096];
  __shared__ int flag;

  const int tid = threadIdx.x;
  const int lane = tid & 63;
  const int w = tid >> 6;  // 0..3
  const int hi = lane >> 5;
  const int l31 = lane & 31;

  // bijective XCD swizzle (768 % 8 == 0)
  const int wg = (blockIdx.x & 7) * 96 + (blockIdx.x >> 3);
  const int bh = wg >> 4, qt = wg & 15;
  const int bb = bh / Hz, h = bh - bb * Hz;
  const int q0 = qt * 128 + w * 32;

  const size_t qkbase = (size_t)bh * Tz * Dz;
  const float* maskp = &mask[bb * Tz];

  if (tid == 0) flag = 0;
  __syncthreads();
  {
    int mybad = 0;
    for (int i = tid; i < Tz; i += 256) mybad |= (maskp[i] != 1.0f);
    if (__any(mybad) && lane == 0) atomicOr(&flag, 1);
  }

  // stage K tiles 0 and 1 into ring slots 0,1
#pragma unroll
  for (int tt = 0; tt < 2; ++tt) {
#pragma unroll
    for (int rep = 0; rep < 2; ++rep) {
      const int c = rep * 256 + tid;  // < 512
      const int row = c >> 3, blk = c & 7;
      const int col = ((blk ^ (row & 7)) << 3);
      gload16(&Kg[qkbase + (size_t)(tt * 64 + row) * Dz + col],
              &Ks[tt][c << 3]);
    }
  }

  // Q B-frags from global (pre-scaled): lane -> q = q0+l31, d = ks*16+hi*8
  bf16x8 qB[4];
#pragma unroll
  for (int ks = 0; ks < 4; ++ks)
    qB[ks] = *reinterpret_cast<const bf16x8*>(
        &Qg[qkbase + (size_t)(q0 + l31) * Dz + ks * 16 + hi * 8]);

  __syncthreads();  // full drain: flag final, K0/K1 staged and landed
  const bool use_mask = (flag != 0);

  // loop-invariant K LDS offsets; (row&7)==(l31&7), kblk adds 2048 elems
  int off4[4];
#pragma unroll
  for (int i = 0; i < 4; ++i)
    off4[i] = l31 * 64 + (((i * 2 + hi) ^ (l31 & 7)) << 3);

  // V chunk lane offset: d=dblk*32+l31 -> (within chunk) d*16 + hi*8
  const int vlane0 = l31 * 16 + hi * 8;
  const size_t vcb0 = qkbase;  // chunked V, key-major, same extent

  f32x16 o0 = {}, o1 = {};
  float lpA = 0.f, lpB = 0.f;

  if (!use_mask) {
    // -------- fast path: counted-vmcnt pipeline --------
    for (int t4 = 0; t4 < 8; ++t4) {
#pragma unroll
      for (int sub = 0; sub < 4; ++sub) {
        const int t = 4 * t4 + sub;
        const int kt = t * 64;
        // (a) vB global loads FIRST (oldest vmem this tile)
        bf16x8 vB[4][2];
#pragma unroll
        for (int ps4 = 0; ps4 < 4; ++ps4) {
          const size_t cb = vcb0 + (size_t)(t * 4 + ps4) * 1024;
          vB[ps4][0] = *reinterpret_cast<const bf16x8*>(&Vc[cb + vlane0]);
          vB[ps4][1] = *reinterpret_cast<const bf16x8*>(&Vc[cb + 512 + vlane0]);
        }
        // (b) compute both kblks (PV consumes vB -> implicitly proves
        //     K(t+1) (older than vB) has landed)
        KBLK_BODY(0, false)
        KBLK_BODY(1, false)
        // (c) prefetch K(t+2) LAST (newest vmem; the only ops vmcnt(2)
        //     leaves in flight)
        if (t < 30) {
          const int kt2 = (t + 2) * 64;
#pragma unroll
          for (int rep = 0; rep < 2; ++rep) {
            const int c = rep * 256 + tid;
            const int row = c >> 3, blk = c & 7;
            const int col = ((blk ^ (row & 7)) << 3);
            gload16(&Kg[qkbase + (size_t)(kt2 + row) * Dz + col],
                    &Ks[(sub + 2) & 3][c << 3]);
          }
        }
        // (d) tail: no drain -- only K(t+2) may remain outstanding
        __builtin_amdgcn_sched_barrier(0);
        asm volatile("s_waitcnt vmcnt(2)");
        __builtin_amdgcn_s_barrier();
        __builtin_amdgcn_sched_barrier(0);
      }
    }
  } else {
    // -------- slow path (mask != all-ones): full drain per tile --------
    for (int t4 = 0; t4 < 8; ++t4) {
#pragma unroll
      for (int sub = 0; sub < 4; ++sub) {
        const int t = 4 * t4 + sub;
        const int kt = t * 64;
        bf16x8 vB[4][2];
#pragma unroll
        for (int ps4 = 0; ps4 < 4; ++ps4) {
          const size_t cb = vcb0 + (size_t)(t * 4 + ps4) * 1024;
          vB[ps4][0] = *reinterpret_cast<const bf16x8*>(&Vc[cb + vlane0]);
          vB[ps4][1] = *reinterpret_cast<const bf16x8*>(&Vc[cb + 512 + vlane0]);
        }
        if (t < 31) {
          const int kt1 = (t + 1) * 64;
#pragma unroll
          for (int rep = 0; rep < 2; ++rep) {
            const int c = rep * 256 + tid;
            const int row = c >> 3, blk = c & 7;
            const int col = ((blk ^ (row & 7)) << 3);
            gload16(&Kg[qkbase + (size_t)(kt1 + row) * Dz + col],
                    &Ks[(sub + 1) & 3][c << 3]);
          }
        }
        KBLK_BODY(0, true)
        KBLK_BODY(1, true)
        __syncthreads();
      }
    }
  }

  // epilogue: O layout col=d=l31(+32*dblk), row=q=(r&3)+8*(r>>2)+4*hi
  float lp = lpA + lpB;
  float lfin = lp + __shfl_xor(lp, 32);
  const float inv = 1.0f / lfin;
#pragma unroll
  for (int r = 0; r < 16; ++r) {
    const int qr = (r & 3) + 8 * (r >> 2) + 4 * hi;
    const float invr = __shfl(inv, qr);  // lanes 0..31 hold inv for q=lane
    float* orow = &out[(size_t)(bb * Tz + q0 + qr) * Cz + h * Dz + l31];
    orow[0] = o0[r] * invr;
    orow[32] = o1[r] * invr;
  }
}

// ---------------- launcher ----------------
extern "C" void kernel_launch(void* const* d_in, const int* in_sizes, int n_in,
                              void* d_out, int out_size, void* d_ws,
                              size_t ws_size, hipStream_t stream) {
  const float* x = (const float*)d_in[0];
  const float* mask = (const float*)d_in[1];
  const float* Wq = (const float*)d_in[2];
  const float* bq = (const float*)d_in[3];
  const float* Wk = (const float*)d_in[4];
  const float* bk = (const float*)d_in[5];
  const float* Wv = (const float*)d_in[6];
  const float* bv = (const float*)d_in[7];
  float* out = (float*)d_out;

  char* ws = (char*)d_ws;
  __bf16* Xb = (__bf16*)ws;                              // 8192*768 bf16
  __bf16* Wb = (__bf16*)(ws + 12582912);                 // 2304*768 bf16
  __bf16* Qb = (__bf16*)(ws + 16131072);                 // [bh][t][d], pre-scaled
  __bf16* Kb = (__bf16*)(ws + 16131072 + 12582912);      // [bh][t][d]
  __bf16* Vb = (__bf16*)(ws + 16131072 + 2 * 12582912);  // chunked [bh][k16][d][kc]

  cvt_all_k<<<7872, 256, 0, stream>>>(x, Wq, Wk, Wv, Xb, Wb);
  qkv_gemm_k<<<1152, 256, 0, stream>>>(Xb, Wb, bq, bk, bv, Qb, Kb, Vb);
  attn_k<<<768, 256, 0, stream>>>(Qb, Kb, Vb, mask, out);
}